// Round 7
// baseline (219.078 us; speedup 1.0000x reference)
//
#include <hip/hip_runtime.h>
#include <hip/hip_bf16.h>

#define T_SEQ 8192
#define E 64
// 0.125 (1/sqrt(64)) * log2(e): softmax computed in exp2 domain
#define QSCALE 0.18033688f

typedef __attribute__((ext_vector_type(4))) float f32x4;
typedef __attribute__((ext_vector_type(8))) short bf16x8;

// 2^x via hardware v_exp_f32 (avoids glibc __exp2f macro collision)
__device__ __forceinline__ float hw_exp2(float x) {
    float r;
    asm("v_exp_f32 %0, %1" : "=v"(r) : "v"(x));
    return r;
}

// packed bf16 pair convert -> v_cvt_pk_bf16_f32
__device__ __forceinline__ unsigned pk2(float a, float b) {
    __hip_bfloat162 h = __float22bfloat162_rn(make_float2(a, b));
    union { __hip_bfloat162 h; unsigned u; } cv; cv.h = h;
    return cv.u;
}

union Frag { unsigned u[4]; bf16x8 v; };

// One block per 64-query slab: 8192 blocks, 4 waves, each wave = 16 queries, single pass.
__global__ __launch_bounds__(256, 2)
void la_kernel(const float* __restrict__ q, const float* __restrict__ k,
               const float* __restrict__ v, float* __restrict__ out) {
    // One 32KB buffer, time-shared: K (bf16, swz) -> V^T (bf16, swz) -> O (fp32, swz)
    __shared__ __align__(16) unsigned char smem[32768];
    unsigned short* KV = (unsigned short*)smem;
    float* OB = (float*)smem;

    const int raw  = blockIdx.x;                      // 0..8191
    // XCD-aware swizzle: adjacent slabs (shared K/V halo) stay on one XCD
    const int work = (raw & 7) * 1024 + (raw >> 3);
    const int bh = work >> 7;
    const int qs = work & 127;      // 64-query slab index
    const int h  = qs & 1;          // half within bucket
    const int qb = qs >> 1;

    const int tid  = threadIdx.x;
    const int wv   = tid >> 6;      // 0..3
    const int lane = tid & 63;
    const int g    = lane >> 4;
    const int col  = lane & 15;

    const size_t base_kv = (size_t)bh * T_SEQ * E;
    const int k0 = qb * 128 - 128;           // window start (may be -128)
    const int KROWS_T = 12 + 4 * h;          // K stage iters (16 rows each): 192 or 256 rows
    const int VPAIR_T = 6 + 2 * h;           // V stage iters (16 pairs each)
    const int STT = (qb == 0) ? 8 : 0;       // first valid key-tile (pad mask)
    const int SKT = (qb == 0) ? 4 : 0;
    const int NT  = 9 + 4 * h + wv;          // key tiles with any unmasked element (wave-uniform)
    const int NKT = (NT + 1) >> 1;

    // ---- Q fragments (single 16-query pass), scale folded into bf16 convert ----
    bf16x8 qf[2];
    #pragma unroll
    for (int kq = 0; kq < 2; ++kq) {
        const float* src = q + ((size_t)bh * T_SEQ + qs * 64 + wv * 16 + col) * E
                             + g * 8 + kq * 32;
        float4 f0 = *(const float4*)(src);
        float4 f1 = *(const float4*)(src + 4);
        Frag fr;
        fr.u[0] = pk2(f0.x * QSCALE, f0.y * QSCALE);
        fr.u[1] = pk2(f0.z * QSCALE, f0.w * QSCALE);
        fr.u[2] = pk2(f1.x * QSCALE, f1.y * QSCALE);
        fr.u[3] = pk2(f1.z * QSCALE, f1.w * QSCALE);
        qf[kq] = fr.v;
    }

    // ---- stage K: fp32 global -> bf16 LDS row-major [j][e], swizzled (only rows needed) ----
    {
        const int jr = tid >> 4;
        const int c4 = (tid & 15) * 4;
        for (int t = 0; t < KROWS_T; ++t) {
            const int jj = jr + t * 16;
            const int gk = k0 + jj;
            float4 kvv = make_float4(0.f, 0.f, 0.f, 0.f);
            if (gk >= 0) kvv = *(const float4*)(k + base_kv + (size_t)gk * E + c4);
            uint2 pr;
            pr.x = pk2(kvv.x, kvv.y);
            pr.y = pk2(kvv.z, kvv.w);
            *(uint2*)(&KV[(jj * 64 + c4) ^ ((jj & 7) << 3)]) = pr;
        }
    }
    __syncthreads();

    // ---- S phase: S^T = K * Q^T (exp2 domain), diag-tile-only mask, softmax, pack bf16 ----
    unsigned P[32];
    float inv;
    {
        f32x4 S[16];
        #pragma unroll
        for (int jt = 0; jt < 16; ++jt) S[jt] = (f32x4)0.f;
        #pragma unroll
        for (int jt = 0; jt < 16; ++jt) {
            if (jt >= STT && jt < NT) {
                const int j = jt * 16 + col;
                #pragma unroll
                for (int kq = 0; kq < 2; ++kq) {
                    const int e = g * 8 + kq * 32;
                    bf16x8 kf = *(const bf16x8*)(&KV[(j * 64 + e) ^ ((j & 7) << 3)]);
                    S[jt] = __builtin_amdgcn_mfma_f32_16x16x32_bf16(kf, qf[kq], S[jt], 0, 0, 0);
                }
            }
        }
        // only the diagonal tile (jt == NT-1) has masked elements: masked iff 4g+r > col
        float mx = -3.0e38f;
        #pragma unroll
        for (int jt = 0; jt < 16; ++jt) {
            if (jt >= STT && jt < NT) {
                if (jt == NT - 1) {              // wave-uniform branch
                    #pragma unroll
                    for (int r = 0; r < 4; ++r) {
                        float s = (4 * g + r <= col) ? S[jt][r] : -1.0e30f;
                        S[jt][r] = s;
                        mx = fmaxf(mx, s);
                    }
                } else {
                    #pragma unroll
                    for (int r = 0; r < 4; ++r) mx = fmaxf(mx, S[jt][r]);
                }
            }
        }
        mx = fmaxf(mx, __shfl_xor(mx, 16, 64));
        mx = fmaxf(mx, __shfl_xor(mx, 32, 64));
        float sum = 0.f;
        #pragma unroll
        for (int jt = 0; jt < 16; ++jt) {
            if (jt >= STT && jt < NT) {
                #pragma unroll
                for (int r = 0; r < 4; ++r) {
                    float p = hw_exp2(S[jt][r] - mx);
                    S[jt][r] = p;
                    sum += p;
                }
            }
        }
        sum += __shfl_xor(sum, 16, 64);
        sum += __shfl_xor(sum, 32, 64);
        inv = 1.0f / sum;
        #pragma unroll
        for (int kt = 0; kt < 8; ++kt) {
            if (kt >= SKT && kt < NKT) {
                // invalid odd tail tile has S == 0.0f from init -> packs to 0
                P[4*kt+0] = pk2(S[2*kt  ][0], S[2*kt  ][1]);
                P[4*kt+1] = pk2(S[2*kt  ][2], S[2*kt  ][3]);
                P[4*kt+2] = pk2(S[2*kt+1][0], S[2*kt+1][1]);
                P[4*kt+3] = pk2(S[2*kt+1][2], S[2*kt+1][3]);
            } else {
                P[4*kt+0] = 0u; P[4*kt+1] = 0u; P[4*kt+2] = 0u; P[4*kt+3] = 0u;
            }
        }
    }
    __syncthreads();   // all waves done reading K

    // ---- stage V: fp32 global -> bf16 LDS transposed [d][j], swizzled (overwrite K) ----
    // 2-lanes/bank write mapping: d-quad = tid>>4, key-pair = tid&15 (+16t)
    {
        const int d0 = (tid >> 4) * 4;
        const int pb = tid & 15;
        for (int t = 0; t < VPAIR_T; ++t) {
            const int p  = pb + 16 * t;
            const int gk = k0 + 2 * p;
            float4 a = make_float4(0.f,0.f,0.f,0.f), b = make_float4(0.f,0.f,0.f,0.f);
            if (gk >= 0) {
                a = *(const float4*)(v + base_kv + (size_t)gk * E + d0);
                b = *(const float4*)(v + base_kv + (size_t)(gk + 1) * E + d0);
            }
            const int jp = 2 * p;
            *(unsigned*)(&KV[((d0    ) * 256 + jp) ^ (((d0    ) & 7) << 3)]) = pk2(a.x, b.x);
            *(unsigned*)(&KV[((d0 + 1) * 256 + jp) ^ (((d0 + 1) & 7) << 3)]) = pk2(a.y, b.y);
            *(unsigned*)(&KV[((d0 + 2) * 256 + jp) ^ (((d0 + 2) & 7) << 3)]) = pk2(a.z, b.z);
            *(unsigned*)(&KV[((d0 + 3) * 256 + jp) ^ (((d0 + 3) & 7) << 3)]) = pk2(a.w, b.w);
        }
    }
    __syncthreads();

    // ---- PV: O = P * V (unnormalized; 1/sum at epilogue) ----
    f32x4 O[4];
    #pragma unroll
    for (int dt = 0; dt < 4; ++dt) O[dt] = (f32x4)0.f;
    {
        const int s0 = ((g & 1) << 5) + col;
        const int s1 = s0 + 16;
        const bool hiSel = (g >= 2);
        #pragma unroll
        for (int kt = 0; kt < 8; ++kt) {
            if (kt >= SKT && kt < NKT) {
                const unsigned x0 = P[4*kt+0], x1 = P[4*kt+1], y0 = P[4*kt+2], y1 = P[4*kt+3];
                unsigned t0x = (unsigned)__shfl((int)x0, s0, 64), t0y = (unsigned)__shfl((int)y0, s0, 64);
                unsigned t1x = (unsigned)__shfl((int)x1, s0, 64), t1y = (unsigned)__shfl((int)y1, s0, 64);
                unsigned t2x = (unsigned)__shfl((int)x0, s1, 64), t2y = (unsigned)__shfl((int)y0, s1, 64);
                unsigned t3x = (unsigned)__shfl((int)x1, s1, 64), t3y = (unsigned)__shfl((int)y1, s1, 64);
                Frag af;
                af.u[0] = hiSel ? t0y : t0x;
                af.u[1] = hiSel ? t1y : t1x;
                af.u[2] = hiSel ? t2y : t2x;
                af.u[3] = hiSel ? t3y : t3x;
                const int j0 = kt * 32 + g * 8;
                #pragma unroll
                for (int dt = 0; dt < 4; ++dt) {
                    const int d = dt * 16 + col;
                    bf16x8 vf = *(const bf16x8*)(&KV[(d * 256 + j0) ^ ((d & 7) << 3)]);
                    O[dt] = __builtin_amdgcn_mfma_f32_16x16x32_bf16(af.v, vf, O[dt], 0, 0, 0);
                }
            }
        }
    }
    __syncthreads();   // all waves done reading V

    // ---- per-output-row 1/sum via shfl (row 4g+r's inv lives at lane with col==4g+r) ----
    const int srcbase = (lane & 48) | ((4 * (lane >> 4)) & 15);
    float w0[4];
    #pragma unroll
    for (int r = 0; r < 4; ++r) w0[r] = __shfl(inv, srcbase + r, 64);

    // ---- bounce O through LDS (fp32, swizzled) for coalesced float4 stores ----
    #pragma unroll
    for (int dt = 0; dt < 4; ++dt) {
        #pragma unroll
        for (int r = 0; r < 4; ++r) {
            const int row = wv * 16 + g * 4 + r;          // 0..63
            const int d = dt * 16 + col;
            OB[(row * 64 + d) ^ ((row & 7) << 2)] = O[dt][r] * w0[r];
        }
    }
    __syncthreads();
    {
        #pragma unroll
        for (int t = 0; t < 4; ++t) {
            const int f4  = t * 256 + tid;
            const int row = f4 >> 4;          // 0..63
            const int c4  = (f4 & 15) * 4;
            float4 val = *(const float4*)(&OB[(row * 64 + c4) ^ ((row & 7) << 2)]);
            *(float4*)(out + ((size_t)bh * T_SEQ + qs * 64 + row) * E + c4) = val;
        }
    }
}

extern "C" void kernel_launch(void* const* d_in, const int* in_sizes, int n_in,
                              void* d_out, int out_size, void* d_ws, size_t ws_size,
                              hipStream_t stream) {
    const float* q = (const float*)d_in[0];
    const float* k = (const float*)d_in[1];
    const float* v = (const float*)d_in[2];
    float* out = (float*)d_out;
    la_kernel<<<dim3(64 * 128), dim3(256), 0, stream>>>(q, k, v, out);
}